// Round 2
// baseline (504.521 us; speedup 1.0000x reference)
//
#include <hip/hip_runtime.h>
#include <hip/hip_bf16.h>
#include <cstdint>

#define N_NODES 8192
#define DDIM    64
#define DX      128
#define NEDGE   262144
#define BR      64
#define BC      64
#define SPLITS  4
#define TILES   (N_NODES / BC / SPLITS)   // 32

typedef float f32x4 __attribute__((ext_vector_type(4)));
typedef short short8 __attribute__((ext_vector_type(8)));

__device__ __forceinline__ short f2bf(float f) {
    union { float f; uint32_t u; } v; v.f = f;
    uint32_t u = v.u;
    uint32_t r = (u + 0x7FFFu + ((u >> 16) & 1u)) >> 16;
    return (short)r;
}
__device__ __forceinline__ float bf2f(short s) {
    union { uint32_t u; float f; } v;
    v.u = ((uint32_t)(uint16_t)s) << 16;
    return v.f;
}

// ---- prep: X = [mag*cos(phase) | mag*sin(phase)] as bf16 [N][128]
__global__ void cpa_prep_x(const float* __restrict__ mag, const float* __restrict__ phase,
                           short* __restrict__ Xbf) {
    int idx = blockIdx.x * 256 + threadIdx.x;      // N*64 threads
    int i = idx >> 6, d = idx & 63;
    float m = mag[idx], p = phase[idx];
    Xbf[i * DX + d]        = f2bf(m * __cosf(p));
    Xbf[i * DX + 64 + d]   = f2bf(m * __sinf(p));
}

// ---- prep: Ybt[c][i] = bf16(Y[i][c]), Y = [mag | phase]  (K-transposed V)
__global__ void cpa_prep_yt(const float* __restrict__ mag, const float* __restrict__ phase,
                            short* __restrict__ Ybt) {
    __shared__ short tile[64][65];
    int bi = blockIdx.x >> 1;
    int bc = blockIdx.x & 1;
    int i0 = bi * 64;
    const float* src = bc ? phase : mag;
    int tid = threadIdx.x;
    for (int itr = 0; itr < 16; ++itr) {
        int idx = tid + itr * 256;                 // 0..4095
        int ii = idx >> 6, cc = idx & 63;
        tile[ii][cc] = f2bf(src[(size_t)(i0 + ii) * 64 + cc]);
    }
    __syncthreads();
    for (int itr = 0; itr < 16; ++itr) {
        int idx = tid + itr * 256;
        int cc = idx >> 6, ii = idx & 63;
        Ybt[(size_t)(bc * 64 + cc) * N_NODES + i0 + ii] = tile[ii][cc];
    }
}

// ---- prep: wsum[k] = sum_h W[h][k], bsum = sum b   (rank-1 collapse of edge Linear)
__global__ void cpa_prep_w(const float* __restrict__ W, const float* __restrict__ b,
                           float* __restrict__ wsb) {
    int t = threadIdx.x;   // 64 threads = 1 wave
    float w0 = W[t * 4 + 0], w1 = W[t * 4 + 1], w2 = W[t * 4 + 2], w3 = W[t * 4 + 3];
    float bb = b[t];
    #pragma unroll
    for (int o = 32; o > 0; o >>= 1) {
        w0 += __shfl_down(w0, o);
        w1 += __shfl_down(w1, o);
        w2 += __shfl_down(w2, o);
        w3 += __shfl_down(w3, o);
        bb += __shfl_down(bb, o);
    }
    if (t == 0) { wsb[0] = w0; wsb[1] = w1; wsb[2] = w2; wsb[3] = w3; wsb[4] = bb; }
}

// ---- edge scores + per-src histogram
__global__ void cpa_edges(const int* __restrict__ ei, const float* __restrict__ ea,
                          const float* __restrict__ wsb, float* __restrict__ es,
                          int* __restrict__ cnt) {
    int e = blockIdx.x * 256 + threadIdx.x;
    float4 a = *(const float4*)(ea + (size_t)e * 4);
    es[e] = a.x * wsb[0] + a.y * wsb[1] + a.z * wsb[2] + a.w * wsb[3] + wsb[4];
    int src = ei[e];
    atomicAdd(&cnt[src], 1);
}

// ---- exclusive scan of 8192 counts (1 block)
__global__ void cpa_scan(const int* __restrict__ cnt, int* __restrict__ rowptr,
                         int* __restrict__ cursor) {
    __shared__ int part[256];
    int t = threadIdx.x;
    int base = t * 32;
    int s = 0;
    for (int k = 0; k < 32; ++k) s += cnt[base + k];
    part[t] = s;
    __syncthreads();
    if (t == 0) {
        int run = 0;
        for (int k = 0; k < 256; ++k) { int tmp = part[k]; part[k] = run; run += tmp; }
        rowptr[N_NODES] = run;
    }
    __syncthreads();
    int run = part[t];
    for (int k = 0; k < 32; ++k) {
        rowptr[base + k] = run;
        cursor[base + k] = run;
        run += cnt[base + k];
    }
}

// ---- scatter edges into CSR, key = (dst<<18)|e  (sortable by (dst, e))
__global__ void cpa_scatter(const int* __restrict__ ei, int* __restrict__ cursor,
                            int* __restrict__ keys) {
    int e = blockIdx.x * 256 + threadIdx.x;
    int src = ei[e];
    int dst = ei[NEDGE + e];
    int pos = atomicAdd(&cursor[src], 1);
    keys[pos] = (dst << 18) | e;
}

// ---- per-row sort by (dst,e); mark all-but-last duplicate dst dead (numpy last-wins)
__global__ void cpa_sortrows(const int* __restrict__ rowptr, int* __restrict__ keys) {
    int i = blockIdx.x * 256 + threadIdx.x;
    if (i >= N_NODES) return;
    int beg = rowptr[i], end = rowptr[i + 1];
    int len = end - beg;
    if (len <= 1) return;
    if (len > 128) len = 128;   // Poisson(32): >128 is ~17 sigma, impossible
    int a[128];
    for (int k = 0; k < len; ++k) a[k] = keys[beg + k];
    for (int k = 1; k < len; ++k) {
        int v = a[k]; int j = k - 1;
        while (j >= 0 && a[j] > v) { a[j + 1] = a[j]; --j; }
        a[j + 1] = v;
    }
    for (int k = 0; k + 1 < len; ++k)
        if ((a[k] >> 18) == (a[k + 1] >> 18)) a[k] |= 0x80000000;  // dead
    for (int k = 0; k < len; ++k) keys[beg + k] = a[k];
}

// ---- flash attention over 64-row block, one column split (2048 cols)
__global__ __launch_bounds__(256) void cpa_flash(
    const short* __restrict__ Xbf, const short* __restrict__ Ybt,
    const float* __restrict__ es, const int* __restrict__ keys,
    const int* __restrict__ rowptr,
    float* __restrict__ msplit, float* __restrict__ lsplit,
    float* __restrict__ Opart)
{
    __shared__ short Xj[BR][136];     // X tile, rows j, stride 136 bf16 (272B, 16B-aligned)
    __shared__ short Yt[DX][72];      // V tile K-transposed: Yt[n][k]
    __shared__ short Pl[BR][72];      // P tile bf16 (C-layout -> A-layout round trip)
    __shared__ int   cur[BR];
    __shared__ int   rend_s[BR];
    __shared__ float dls[BR];

    const int tid   = threadIdx.x;
    const int lane  = tid & 63;
    const int w     = tid >> 6;       // wave 0..3 -> rows 16w..16w+15
    const int q     = lane >> 4;      // quad
    const int colid = lane & 15;

    const int ib = blockIdx.x;        // 0..127
    const int split = blockIdx.y;     // 0..SPLITS-1
    const int i0 = ib * BR;
    const int jstart = split * (N_NODES / SPLITS);

    // load Xi rows into Xj buffer, pull A-fragments to registers (once per block)
    for (int itr = 0; itr < 4; ++itr) {
        int idx = tid + itr * 256;
        int r = idx >> 4;
        int c8 = (idx & 15) << 3;
        *(int4*)(&Xj[r][c8]) = *(const int4*)(Xbf + (size_t)(i0 + r) * DX + c8);
    }
    __syncthreads();
    short8 afrag[4];
    #pragma unroll
    for (int kf = 0; kf < 4; ++kf)
        afrag[kf] = *(const short8*)&Xj[w * 16 + colid][kf * 32 + q * 8];  // FIX: wave w owns rows 16w..16w+15
    if (tid < BR) {
        int i = i0 + tid;
        int c = rowptr[i], e_ = rowptr[i + 1];
        while (c < e_) {
            int k = keys[c];
            int dst = (k >> 18) & 0x1FFF;
            if (dst >= jstart) break;
            ++c;
        }
        cur[tid] = c; rend_s[tid] = e_;
        dls[tid] = 0.f;
    }
    __syncthreads();

    float m_r[4] = {-1e30f, -1e30f, -1e30f, -1e30f};
    float l_r[4] = {0.f, 0.f, 0.f, 0.f};
    f32x4 O[8];
    #pragma unroll
    for (int t = 0; t < 8; ++t) O[t] = (f32x4){0.f, 0.f, 0.f, 0.f};

    for (int tt = 0; tt < TILES; ++tt) {
        const int j0 = jstart + tt * BC;
        // phase A: stage X_j and Y_t tiles
        for (int itr = 0; itr < 4; ++itr) {
            int idx = tid + itr * 256;
            int r = idx >> 4;
            int c8 = (idx & 15) << 3;
            *(int4*)(&Xj[r][c8]) = *(const int4*)(Xbf + (size_t)(j0 + r) * DX + c8);
        }
        for (int itr = 0; itr < 4; ++itr) {
            int idx = tid + itr * 256;
            int n = idx >> 3;
            int k8 = (idx & 7) << 3;
            *(int4*)(&Yt[n][k8]) = *(const int4*)(Ybt + (size_t)n * N_NODES + j0 + k8);
        }
        __syncthreads();  // B1

        // phase B: S = Xi·Xjᵀ (wave w: rows 16w..16w+15, cols 0..63)
        f32x4 S[4];
        #pragma unroll
        for (int st = 0; st < 4; ++st) {
            f32x4 acc = (f32x4){0.f, 0.f, 0.f, 0.f};
            #pragma unroll
            for (int kf = 0; kf < 4; ++kf) {
                short8 bfrag = *(const short8*)&Xj[st * 16 + colid][kf * 32 + q * 8];
                acc = __builtin_amdgcn_mfma_f32_16x16x32_bf16(afrag[kf], bfrag, acc, 0, 0, 0);
            }
            S[st] = acc;
        }
        // online softmax (C-layout: row = q*4+r local-16, col = st*16+colid)
        float mnew[4], alpha[4];
        #pragma unroll
        for (int r = 0; r < 4; ++r) {
            float mx = fmaxf(fmaxf(S[0][r], S[1][r]), fmaxf(S[2][r], S[3][r]));
            mx = fmaxf(mx, __shfl_xor(mx, 1));
            mx = fmaxf(mx, __shfl_xor(mx, 2));
            mx = fmaxf(mx, __shfl_xor(mx, 4));
            mx = fmaxf(mx, __shfl_xor(mx, 8));
            mnew[r] = fmaxf(m_r[r], mx);
            alpha[r] = __expf(m_r[r] - mnew[r]);
            m_r[r] = mnew[r];
        }
        float rsum[4] = {0.f, 0.f, 0.f, 0.f};
        short pb[4][4];
        #pragma unroll
        for (int st = 0; st < 4; ++st) {
            #pragma unroll
            for (int r = 0; r < 4; ++r) {
                float p = __expf(S[st][r] - mnew[r]);
                rsum[r] += p;
                pb[st][r] = f2bf(p);
            }
        }
        #pragma unroll
        for (int r = 0; r < 4; ++r) {
            float s_ = rsum[r];
            s_ += __shfl_xor(s_, 1);
            s_ += __shfl_xor(s_, 2);
            s_ += __shfl_xor(s_, 4);
            s_ += __shfl_xor(s_, 8);
            l_r[r] = l_r[r] * alpha[r] + s_;
            #pragma unroll
            for (int t = 0; t < 8; ++t) O[t][r] *= alpha[r];
        }
        // phase C: P -> LDS (bf16)
        #pragma unroll
        for (int st = 0; st < 4; ++st)
            #pragma unroll
            for (int r = 0; r < 4; ++r)
                Pl[w * 16 + q * 4 + r][st * 16 + colid] = pb[st][r];
        __syncthreads();  // B3

        // phase C2: sparse bias: P *= exp(bias) at live edges; track Δl per row
        if (tid < BR) {
            int c = cur[tid];
            const int e_ = rend_s[tid];
            const int jend = j0 + BC;
            float dlocal = 0.f;
            while (c < e_) {
                int k = keys[c];
                int dst = (k >> 18) & 0x1FFF;
                if (dst >= jend) break;
                ++c;
                if (k >= 0) {  // live (last duplicate wins)
                    int ec = dst - j0;
                    float old = bf2f(Pl[tid][ec]);
                    float nw = old * __expf(es[k & 0x3FFFF]);
                    Pl[tid][ec] = f2bf(nw);
                    dlocal += nw - old;
                }
            }
            cur[tid] = c;
            dls[tid] = dlocal;
        }
        __syncthreads();  // B3.5

        // phase D: l += Δl; O += P·Y
        #pragma unroll
        for (int r = 0; r < 4; ++r)
            l_r[r] += dls[w * 16 + q * 4 + r];

        short8 pf0 = *(const short8*)&Pl[w * 16 + colid][q * 8];
        short8 pf1 = *(const short8*)&Pl[w * 16 + colid][32 + q * 8];
        #pragma unroll
        for (int t = 0; t < 8; ++t) {
            short8 b0 = *(const short8*)&Yt[t * 16 + colid][q * 8];
            short8 b1 = *(const short8*)&Yt[t * 16 + colid][32 + q * 8];
            O[t] = __builtin_amdgcn_mfma_f32_16x16x32_bf16(pf0, b0, O[t], 0, 0, 0);
            O[t] = __builtin_amdgcn_mfma_f32_16x16x32_bf16(pf1, b1, O[t], 0, 0, 0);
        }
        __syncthreads();  // B4 (protect tiles for next iteration)
    }

    // epilogue: store partial m, l, O
    const int ibase = i0 + w * 16 + q * 4;
    #pragma unroll
    for (int r = 0; r < 4; ++r) {
        if (colid == r) {
            msplit[(size_t)split * N_NODES + ibase + r] = m_r[r];
            lsplit[(size_t)split * N_NODES + ibase + r] = l_r[r];
        }
    }
    #pragma unroll
    for (int t = 0; t < 8; ++t) {
        #pragma unroll
        for (int r = 0; r < 4; ++r) {
            size_t off = ((size_t)split * N_NODES + ibase + r) * DX + t * 16 + colid;
            Opart[off] = O[t][r];
        }
    }
}

// ---- merge splits + normalize + write [new_mag | new_phase]
__global__ void cpa_merge(const float* __restrict__ msplit, const float* __restrict__ lsplit,
                          const float* __restrict__ Opart, float* __restrict__ out) {
    int gid = blockIdx.x * 256 + threadIdx.x;   // N*128 threads
    int i = gid >> 7;
    int c = gid & 127;
    float mm = -1e30f;
    #pragma unroll
    for (int s = 0; s < SPLITS; ++s) mm = fmaxf(mm, msplit[(size_t)s * N_NODES + i]);
    float den = 0.f, num = 0.f;
    #pragma unroll
    for (int s = 0; s < SPLITS; ++s) {
        float wgt = __expf(msplit[(size_t)s * N_NODES + i] - mm);
        den += lsplit[(size_t)s * N_NODES + i] * wgt;
        num += Opart[((size_t)s * N_NODES + i) * DX + c] * wgt;
    }
    float val = num / den;
    if (c < 64) out[(size_t)i * 64 + c] = val;
    else        out[(size_t)N_NODES * 64 + (size_t)i * 64 + (c - 64)] = val;
}

extern "C" void kernel_launch(void* const* d_in, const int* in_sizes, int n_in,
                              void* d_out, int out_size, void* d_ws, size_t ws_size,
                              hipStream_t stream)
{
    const float* mag   = (const float*)d_in[0];
    const float* phase = (const float*)d_in[1];
    const int*   ei    = (const int*)d_in[2];     // edge_index [2][E] (int32 per harness)
    const float* ea    = (const float*)d_in[3];
    const float* W     = (const float*)d_in[4];
    const float* b     = (const float*)d_in[5];
    float* out = (float*)d_out;

    char* ws = (char*)d_ws;
    short* Xbf    = (short*)(ws + 0);               // 2 MB
    short* Ybt    = (short*)(ws + 2097152);         // 2 MB
    float* es     = (float*)(ws + 4194304);         // 1 MB
    int*   keys   = (int*)  (ws + 5242880);         // 1 MB
    int*   rowptr = (int*)  (ws + 6291456);         // 36 KB slot
    int*   cnt    = (int*)  (ws + 6328320);         // 32 KB
    int*   cursor = (int*)  (ws + 6361088);         // 32 KB
    float* wsb    = (float*)(ws + 6393856);         // 256 B
    float* msplit = (float*)(ws + 6394112);         // 128 KB
    float* lsplit = (float*)(ws + 6525184);         // 128 KB
    float* Opart  = (float*)(ws + 6656256);         // 16 MB

    hipMemsetAsync(cnt, 0, N_NODES * sizeof(int), stream);
    cpa_prep_x<<<N_NODES * DDIM / 256, 256, 0, stream>>>(mag, phase, Xbf);
    cpa_prep_yt<<<(N_NODES / 64) * 2, 256, 0, stream>>>(mag, phase, Ybt);
    cpa_prep_w<<<1, 64, 0, stream>>>(W, b, wsb);
    cpa_edges<<<NEDGE / 256, 256, 0, stream>>>(ei, ea, wsb, es, cnt);
    cpa_scan<<<1, 256, 0, stream>>>(cnt, rowptr, cursor);
    cpa_scatter<<<NEDGE / 256, 256, 0, stream>>>(ei, cursor, keys);
    cpa_sortrows<<<N_NODES / 256, 256, 0, stream>>>(rowptr, keys);
    cpa_flash<<<dim3(N_NODES / BR, SPLITS), 256, 0, stream>>>(Xbf, Ybt, es, keys, rowptr,
                                                              msplit, lsplit, Opart);
    cpa_merge<<<N_NODES * DX / 256, 256, 0, stream>>>(msplit, lsplit, Opart, out);
}

// Round 3
// 290.311 us; speedup vs baseline: 1.7379x; 1.7379x over previous
//
#include <hip/hip_runtime.h>
#include <hip/hip_bf16.h>
#include <cstdint>

#define N_NODES 8192
#define DDIM    64
#define DX      128
#define NEDGE   262144
#define BR      64
#define BC      64
#define SPLITS  4
#define TILES   (N_NODES / BC / SPLITS)   // 32

typedef float f32x4 __attribute__((ext_vector_type(4)));
typedef short short8 __attribute__((ext_vector_type(8)));

__device__ __forceinline__ short f2bf(float f) {
    union { float f; uint32_t u; } v; v.f = f;
    uint32_t u = v.u;
    uint32_t r = (u + 0x7FFFu + ((u >> 16) & 1u)) >> 16;
    return (short)r;
}
__device__ __forceinline__ float bf2f(short s) {
    union { uint32_t u; float f; } v;
    v.u = ((uint32_t)(uint16_t)s) << 16;
    return v.f;
}

// ---- prep: X = [mag*cos(phase) | mag*sin(phase)] as bf16 [N][128]
__global__ void cpa_prep_x(const float* __restrict__ mag, const float* __restrict__ phase,
                           short* __restrict__ Xbf) {
    int idx = blockIdx.x * 256 + threadIdx.x;      // N*64 threads
    int i = idx >> 6, d = idx & 63;
    float m = mag[idx], p = phase[idx];
    Xbf[i * DX + d]        = f2bf(m * __cosf(p));
    Xbf[i * DX + 64 + d]   = f2bf(m * __sinf(p));
}

// ---- prep: Ybt[c][i] = bf16(Y[i][c]), Y = [mag | phase]  (K-transposed V)
__global__ void cpa_prep_yt(const float* __restrict__ mag, const float* __restrict__ phase,
                            short* __restrict__ Ybt) {
    __shared__ short tile[64][65];
    int bi = blockIdx.x >> 1;
    int bc = blockIdx.x & 1;
    int i0 = bi * 64;
    const float* src = bc ? phase : mag;
    int tid = threadIdx.x;
    for (int itr = 0; itr < 16; ++itr) {
        int idx = tid + itr * 256;                 // 0..4095
        int ii = idx >> 6, cc = idx & 63;
        tile[ii][cc] = f2bf(src[(size_t)(i0 + ii) * 64 + cc]);
    }
    __syncthreads();
    for (int itr = 0; itr < 16; ++itr) {
        int idx = tid + itr * 256;
        int cc = idx >> 6, ii = idx & 63;
        Ybt[(size_t)(bc * 64 + cc) * N_NODES + i0 + ii] = tile[ii][cc];
    }
}

// ---- prep: wsum[k] = sum_h W[h][k], bsum = sum b   (rank-1 collapse of edge Linear)
__global__ void cpa_prep_w(const float* __restrict__ W, const float* __restrict__ b,
                           float* __restrict__ wsb) {
    int t = threadIdx.x;   // 64 threads = 1 wave
    float w0 = W[t * 4 + 0], w1 = W[t * 4 + 1], w2 = W[t * 4 + 2], w3 = W[t * 4 + 3];
    float bb = b[t];
    #pragma unroll
    for (int o = 32; o > 0; o >>= 1) {
        w0 += __shfl_down(w0, o);
        w1 += __shfl_down(w1, o);
        w2 += __shfl_down(w2, o);
        w3 += __shfl_down(w3, o);
        bb += __shfl_down(bb, o);
    }
    if (t == 0) { wsb[0] = w0; wsb[1] = w1; wsb[2] = w2; wsb[3] = w3; wsb[4] = bb; }
}

// ---- edge scores + per-src histogram
__global__ void cpa_edges(const int* __restrict__ ei, const float* __restrict__ ea,
                          const float* __restrict__ wsb, float* __restrict__ es,
                          int* __restrict__ cnt) {
    int e = blockIdx.x * 256 + threadIdx.x;
    float4 a = *(const float4*)(ea + (size_t)e * 4);
    es[e] = a.x * wsb[0] + a.y * wsb[1] + a.z * wsb[2] + a.w * wsb[3] + wsb[4];
    int src = ei[e];
    atomicAdd(&cnt[src], 1);
}

// ---- exclusive scan of 8192 counts (1 block)
__global__ void cpa_scan(const int* __restrict__ cnt, int* __restrict__ rowptr,
                         int* __restrict__ cursor) {
    __shared__ int part[256];
    int t = threadIdx.x;
    int base = t * 32;
    int s = 0;
    for (int k = 0; k < 32; ++k) s += cnt[base + k];
    part[t] = s;
    __syncthreads();
    if (t == 0) {
        int run = 0;
        for (int k = 0; k < 256; ++k) { int tmp = part[k]; part[k] = run; run += tmp; }
        rowptr[N_NODES] = run;
    }
    __syncthreads();
    int run = part[t];
    for (int k = 0; k < 32; ++k) {
        rowptr[base + k] = run;
        cursor[base + k] = run;
        run += cnt[base + k];
    }
}

// ---- scatter edges into CSR, key = (dst<<18)|e  (sortable by (dst, e))
__global__ void cpa_scatter(const int* __restrict__ ei, int* __restrict__ cursor,
                            int* __restrict__ keys) {
    int e = blockIdx.x * 256 + threadIdx.x;
    int src = ei[e];
    int dst = ei[NEDGE + e];
    int pos = atomicAdd(&cursor[src], 1);
    keys[pos] = (dst << 18) | e;
}

// ---- per-row sort by (dst,e) via wave-parallel bitonic (2 keys/lane, len<=128);
// mark all-but-last duplicate dst dead (numpy last-wins). No scratch, no LDS.
__global__ __launch_bounds__(256) void cpa_sortrows(const int* __restrict__ rowptr,
                                                    int* __restrict__ keys) {
    int row  = blockIdx.x * 4 + (threadIdx.x >> 6);   // one wave per row
    int lane = threadIdx.x & 63;
    int beg = rowptr[row], end = rowptr[row + 1];
    int len = end - beg;
    if (len > 128) len = 128;   // Poisson(32): impossible in practice
    const int idx0 = lane * 2, idx1 = lane * 2 + 1;
    int v0 = (idx0 < len) ? keys[beg + idx0] : 0x7FFFFFFF;
    int v1 = (idx1 < len) ? keys[beg + idx1] : 0x7FFFFFFF;

    #pragma unroll
    for (int k = 2; k <= 128; k <<= 1) {
        #pragma unroll
        for (int j = k >> 1; j >= 2; j >>= 1) {
            int ldist = j >> 1;                        // partner lane distance
            int p0 = __shfl_xor(v0, ldist);
            int p1 = __shfl_xor(v1, ldist);
            bool asc = (idx0 & k) == 0;                // same for both slots (k>=2)
            bool low = (idx0 & j) == 0;                // same for both slots (j>=2)
            int n0 = (low == asc) ? min(v0, p0) : max(v0, p0);
            int n1 = (low == asc) ? min(v1, p1) : max(v1, p1);
            v0 = n0; v1 = n1;
        }
        {   // j == 1: within-lane compare of the two slots
            bool asc = (idx0 & k) == 0;
            int lo = min(v0, v1), hi = max(v0, v1);
            v0 = asc ? lo : hi;
            v1 = asc ? hi : lo;
        }
    }

    // mark dead: element idx is dead iff idx+1 < len and dst(idx+1)==dst(idx).
    // (pads are 0x7FFFFFFF which aliases a representable key -> must guard by len)
    int nextv0 = __shfl_down(v0, 1);                   // lane+1's v0 = element idx1+1
    bool dead0 = (idx0 + 1 < len) && ((v0 >> 18) == (v1 >> 18));
    bool dead1 = (idx1 + 1 < len) && ((v1 >> 18) == (nextv0 >> 18));
    if (idx0 < len) keys[beg + idx0] = v0 | (dead0 ? 0x80000000 : 0);
    if (idx1 < len) keys[beg + idx1] = v1 | (dead1 ? 0x80000000 : 0);
}

// ---- flash attention over 64-row block, one column split (2048 cols)
__global__ __launch_bounds__(256) void cpa_flash(
    const short* __restrict__ Xbf, const short* __restrict__ Ybt,
    const float* __restrict__ es, const int* __restrict__ keys,
    const int* __restrict__ rowptr,
    float* __restrict__ msplit, float* __restrict__ lsplit,
    float* __restrict__ Opart)
{
    __shared__ short Xj[BR][136];     // X tile, rows j, stride 136 bf16 (272B, 16B-aligned)
    __shared__ short Yt[DX][72];      // V tile K-transposed: Yt[n][k]
    __shared__ short Pl[BR][72];      // P tile bf16 (C-layout -> A-layout round trip)
    __shared__ int   cur[BR];
    __shared__ int   rend_s[BR];
    __shared__ float dls[BR];

    const int tid   = threadIdx.x;
    const int lane  = tid & 63;
    const int w     = tid >> 6;       // wave 0..3 -> rows 16w..16w+15
    const int q     = lane >> 4;      // quad
    const int colid = lane & 15;

    const int ib = blockIdx.x;        // 0..127
    const int split = blockIdx.y;     // 0..SPLITS-1
    const int i0 = ib * BR;
    const int jstart = split * (N_NODES / SPLITS);

    // load Xi rows into Xj buffer, pull A-fragments to registers (once per block)
    for (int itr = 0; itr < 4; ++itr) {
        int idx = tid + itr * 256;
        int r = idx >> 4;
        int c8 = (idx & 15) << 3;
        *(int4*)(&Xj[r][c8]) = *(const int4*)(Xbf + (size_t)(i0 + r) * DX + c8);
    }
    __syncthreads();
    short8 afrag[4];
    #pragma unroll
    for (int kf = 0; kf < 4; ++kf)
        afrag[kf] = *(const short8*)&Xj[w * 16 + colid][kf * 32 + q * 8];  // wave w owns rows 16w..16w+15
    if (tid < BR) {
        int i = i0 + tid;
        int c = rowptr[i], e_ = rowptr[i + 1];
        while (c < e_) {
            int k = keys[c];
            int dst = (k >> 18) & 0x1FFF;
            if (dst >= jstart) break;
            ++c;
        }
        cur[tid] = c; rend_s[tid] = e_;
        dls[tid] = 0.f;
    }
    __syncthreads();

    float m_r[4] = {-1e30f, -1e30f, -1e30f, -1e30f};
    float l_r[4] = {0.f, 0.f, 0.f, 0.f};
    f32x4 O[8];
    #pragma unroll
    for (int t = 0; t < 8; ++t) O[t] = (f32x4){0.f, 0.f, 0.f, 0.f};

    for (int tt = 0; tt < TILES; ++tt) {
        const int j0 = jstart + tt * BC;
        // phase A: stage X_j and Y_t tiles
        for (int itr = 0; itr < 4; ++itr) {
            int idx = tid + itr * 256;
            int r = idx >> 4;
            int c8 = (idx & 15) << 3;
            *(int4*)(&Xj[r][c8]) = *(const int4*)(Xbf + (size_t)(j0 + r) * DX + c8);
        }
        for (int itr = 0; itr < 4; ++itr) {
            int idx = tid + itr * 256;
            int n = idx >> 3;
            int k8 = (idx & 7) << 3;
            *(int4*)(&Yt[n][k8]) = *(const int4*)(Ybt + (size_t)n * N_NODES + j0 + k8);
        }
        __syncthreads();  // B1

        // phase B: S = Xi·Xjᵀ (wave w: rows 16w..16w+15, cols 0..63)
        f32x4 S[4];
        #pragma unroll
        for (int st = 0; st < 4; ++st) {
            f32x4 acc = (f32x4){0.f, 0.f, 0.f, 0.f};
            #pragma unroll
            for (int kf = 0; kf < 4; ++kf) {
                short8 bfrag = *(const short8*)&Xj[st * 16 + colid][kf * 32 + q * 8];
                acc = __builtin_amdgcn_mfma_f32_16x16x32_bf16(afrag[kf], bfrag, acc, 0, 0, 0);
            }
            S[st] = acc;
        }
        // online softmax (C-layout: row = q*4+r local-16, col = st*16+colid)
        float mnew[4], alpha[4];
        #pragma unroll
        for (int r = 0; r < 4; ++r) {
            float mx = fmaxf(fmaxf(S[0][r], S[1][r]), fmaxf(S[2][r], S[3][r]));
            mx = fmaxf(mx, __shfl_xor(mx, 1));
            mx = fmaxf(mx, __shfl_xor(mx, 2));
            mx = fmaxf(mx, __shfl_xor(mx, 4));
            mx = fmaxf(mx, __shfl_xor(mx, 8));
            mnew[r] = fmaxf(m_r[r], mx);
            alpha[r] = __expf(m_r[r] - mnew[r]);
            m_r[r] = mnew[r];
        }
        float rsum[4] = {0.f, 0.f, 0.f, 0.f};
        short pb[4][4];
        #pragma unroll
        for (int st = 0; st < 4; ++st) {
            #pragma unroll
            for (int r = 0; r < 4; ++r) {
                float p = __expf(S[st][r] - mnew[r]);
                rsum[r] += p;
                pb[st][r] = f2bf(p);
            }
        }
        #pragma unroll
        for (int r = 0; r < 4; ++r) {
            float s_ = rsum[r];
            s_ += __shfl_xor(s_, 1);
            s_ += __shfl_xor(s_, 2);
            s_ += __shfl_xor(s_, 4);
            s_ += __shfl_xor(s_, 8);
            l_r[r] = l_r[r] * alpha[r] + s_;
            #pragma unroll
            for (int t = 0; t < 8; ++t) O[t][r] *= alpha[r];
        }
        // phase C: P -> LDS (bf16)
        #pragma unroll
        for (int st = 0; st < 4; ++st)
            #pragma unroll
            for (int r = 0; r < 4; ++r)
                Pl[w * 16 + q * 4 + r][st * 16 + colid] = pb[st][r];
        __syncthreads();  // B3

        // phase C2: sparse bias: P *= exp(bias) at live edges; track Δl per row
        if (tid < BR) {
            int c = cur[tid];
            const int e_ = rend_s[tid];
            const int jend = j0 + BC;
            float dlocal = 0.f;
            while (c < e_) {
                int k = keys[c];
                int dst = (k >> 18) & 0x1FFF;
                if (dst >= jend) break;
                ++c;
                if (k >= 0) {  // live (last duplicate wins)
                    int ec = dst - j0;
                    float old = bf2f(Pl[tid][ec]);
                    float nw = old * __expf(es[k & 0x3FFFF]);
                    Pl[tid][ec] = f2bf(nw);
                    dlocal += nw - old;
                }
            }
            cur[tid] = c;
            dls[tid] = dlocal;
        }
        __syncthreads();  // B3.5

        // phase D: l += Δl; O += P·Y
        #pragma unroll
        for (int r = 0; r < 4; ++r)
            l_r[r] += dls[w * 16 + q * 4 + r];

        short8 pf0 = *(const short8*)&Pl[w * 16 + colid][q * 8];
        short8 pf1 = *(const short8*)&Pl[w * 16 + colid][32 + q * 8];
        #pragma unroll
        for (int t = 0; t < 8; ++t) {
            short8 b0 = *(const short8*)&Yt[t * 16 + colid][q * 8];
            short8 b1 = *(const short8*)&Yt[t * 16 + colid][32 + q * 8];
            O[t] = __builtin_amdgcn_mfma_f32_16x16x32_bf16(pf0, b0, O[t], 0, 0, 0);
            O[t] = __builtin_amdgcn_mfma_f32_16x16x32_bf16(pf1, b1, O[t], 0, 0, 0);
        }
        __syncthreads();  // B4 (protect tiles for next iteration)
    }

    // epilogue: store partial m, l, O
    const int ibase = i0 + w * 16 + q * 4;
    #pragma unroll
    for (int r = 0; r < 4; ++r) {
        if (colid == r) {
            msplit[(size_t)split * N_NODES + ibase + r] = m_r[r];
            lsplit[(size_t)split * N_NODES + ibase + r] = l_r[r];
        }
    }
    #pragma unroll
    for (int t = 0; t < 8; ++t) {
        #pragma unroll
        for (int r = 0; r < 4; ++r) {
            size_t off = ((size_t)split * N_NODES + ibase + r) * DX + t * 16 + colid;
            Opart[off] = O[t][r];
        }
    }
}

// ---- merge splits + normalize + write [new_mag | new_phase]
__global__ void cpa_merge(const float* __restrict__ msplit, const float* __restrict__ lsplit,
                          const float* __restrict__ Opart, float* __restrict__ out) {
    int gid = blockIdx.x * 256 + threadIdx.x;   // N*128 threads
    int i = gid >> 7;
    int c = gid & 127;
    float mm = -1e30f;
    #pragma unroll
    for (int s = 0; s < SPLITS; ++s) mm = fmaxf(mm, msplit[(size_t)s * N_NODES + i]);
    float den = 0.f, num = 0.f;
    #pragma unroll
    for (int s = 0; s < SPLITS; ++s) {
        float wgt = __expf(msplit[(size_t)s * N_NODES + i] - mm);
        den += lsplit[(size_t)s * N_NODES + i] * wgt;
        num += Opart[((size_t)s * N_NODES + i) * DX + c] * wgt;
    }
    float val = num / den;
    if (c < 64) out[(size_t)i * 64 + c] = val;
    else        out[(size_t)N_NODES * 64 + (size_t)i * 64 + (c - 64)] = val;
}

extern "C" void kernel_launch(void* const* d_in, const int* in_sizes, int n_in,
                              void* d_out, int out_size, void* d_ws, size_t ws_size,
                              hipStream_t stream)
{
    const float* mag   = (const float*)d_in[0];
    const float* phase = (const float*)d_in[1];
    const int*   ei    = (const int*)d_in[2];     // edge_index [2][E] (int32 per harness)
    const float* ea    = (const float*)d_in[3];
    const float* W     = (const float*)d_in[4];
    const float* b     = (const float*)d_in[5];
    float* out = (float*)d_out;

    char* ws = (char*)d_ws;
    short* Xbf    = (short*)(ws + 0);               // 2 MB
    short* Ybt    = (short*)(ws + 2097152);         // 2 MB
    float* es     = (float*)(ws + 4194304);         // 1 MB
    int*   keys   = (int*)  (ws + 5242880);         // 1 MB
    int*   rowptr = (int*)  (ws + 6291456);         // 36 KB slot
    int*   cnt    = (int*)  (ws + 6328320);         // 32 KB
    int*   cursor = (int*)  (ws + 6361088);         // 32 KB
    float* wsb    = (float*)(ws + 6393856);         // 256 B
    float* msplit = (float*)(ws + 6394112);         // 128 KB
    float* lsplit = (float*)(ws + 6525184);         // 128 KB
    float* Opart  = (float*)(ws + 6656256);         // 16 MB

    hipMemsetAsync(cnt, 0, N_NODES * sizeof(int), stream);
    cpa_prep_x<<<N_NODES * DDIM / 256, 256, 0, stream>>>(mag, phase, Xbf);
    cpa_prep_yt<<<(N_NODES / 64) * 2, 256, 0, stream>>>(mag, phase, Ybt);
    cpa_prep_w<<<1, 64, 0, stream>>>(W, b, wsb);
    cpa_edges<<<NEDGE / 256, 256, 0, stream>>>(ei, ea, wsb, es, cnt);
    cpa_scan<<<1, 256, 0, stream>>>(cnt, rowptr, cursor);
    cpa_scatter<<<NEDGE / 256, 256, 0, stream>>>(ei, cursor, keys);
    cpa_sortrows<<<N_NODES / 4, 256, 0, stream>>>(rowptr, keys);
    cpa_flash<<<dim3(N_NODES / BR, SPLITS), 256, 0, stream>>>(Xbf, Ybt, es, keys, rowptr,
                                                              msplit, lsplit, Opart);
    cpa_merge<<<N_NODES * DX / 256, 256, 0, stream>>>(msplit, lsplit, Opart, out);
}

// Round 4
// 285.078 us; speedup vs baseline: 1.7698x; 1.0184x over previous
//
#include <hip/hip_runtime.h>
#include <hip/hip_bf16.h>
#include <cstdint>

#define N_NODES 8192
#define DDIM    64
#define DX      128
#define NEDGE   262144
#define BR      64
#define BC      64
#define SPLITS  8
#define TILES   (N_NODES / BC / SPLITS)   // 16

typedef float f32x4 __attribute__((ext_vector_type(4)));
typedef short short8 __attribute__((ext_vector_type(8)));

__device__ __forceinline__ short f2bf(float f) {
    union { float f; uint32_t u; } v; v.f = f;
    uint32_t u = v.u;
    uint32_t r = (u + 0x7FFFu + ((u >> 16) & 1u)) >> 16;
    return (short)r;
}
__device__ __forceinline__ float bf2f(short s) {
    union { uint32_t u; float f; } v;
    v.u = ((uint32_t)(uint16_t)s) << 16;
    return v.f;
}

// ---- prep: X = [mag*cos(phase) | mag*sin(phase)] as bf16 [N][128]
__global__ void cpa_prep_x(const float* __restrict__ mag, const float* __restrict__ phase,
                           short* __restrict__ Xbf) {
    int idx = blockIdx.x * 256 + threadIdx.x;      // N*64 threads
    int i = idx >> 6, d = idx & 63;
    float m = mag[idx], p = phase[idx];
    Xbf[i * DX + d]        = f2bf(m * __cosf(p));
    Xbf[i * DX + 64 + d]   = f2bf(m * __sinf(p));
}

// ---- prep: Ybt[c][i] = bf16(Y[i][c]), Y = [mag | phase]  (K-transposed V)
__global__ void cpa_prep_yt(const float* __restrict__ mag, const float* __restrict__ phase,
                            short* __restrict__ Ybt) {
    __shared__ short tile[64][65];
    int bi = blockIdx.x >> 1;
    int bc = blockIdx.x & 1;
    int i0 = bi * 64;
    const float* src = bc ? phase : mag;
    int tid = threadIdx.x;
    for (int itr = 0; itr < 16; ++itr) {
        int idx = tid + itr * 256;                 // 0..4095
        int ii = idx >> 6, cc = idx & 63;
        tile[ii][cc] = f2bf(src[(size_t)(i0 + ii) * 64 + cc]);
    }
    __syncthreads();
    for (int itr = 0; itr < 16; ++itr) {
        int idx = tid + itr * 256;
        int cc = idx >> 6, ii = idx & 63;
        Ybt[(size_t)(bc * 64 + cc) * N_NODES + i0 + ii] = tile[ii][cc];
    }
}

// ---- prep: wsum[k] = sum_h W[h][k], bsum = sum b   (rank-1 collapse of edge Linear)
__global__ void cpa_prep_w(const float* __restrict__ W, const float* __restrict__ b,
                           float* __restrict__ wsb) {
    int t = threadIdx.x;   // 64 threads = 1 wave
    float w0 = W[t * 4 + 0], w1 = W[t * 4 + 1], w2 = W[t * 4 + 2], w3 = W[t * 4 + 3];
    float bb = b[t];
    #pragma unroll
    for (int o = 32; o > 0; o >>= 1) {
        w0 += __shfl_down(w0, o);
        w1 += __shfl_down(w1, o);
        w2 += __shfl_down(w2, o);
        w3 += __shfl_down(w3, o);
        bb += __shfl_down(bb, o);
    }
    if (t == 0) { wsb[0] = w0; wsb[1] = w1; wsb[2] = w2; wsb[3] = w3; wsb[4] = bb; }
}

// ---- edge scores + per-src histogram
__global__ void cpa_edges(const int* __restrict__ ei, const float* __restrict__ ea,
                          const float* __restrict__ wsb, float* __restrict__ es,
                          int* __restrict__ cnt) {
    int e = blockIdx.x * 256 + threadIdx.x;
    float4 a = *(const float4*)(ea + (size_t)e * 4);
    es[e] = a.x * wsb[0] + a.y * wsb[1] + a.z * wsb[2] + a.w * wsb[3] + wsb[4];
    int src = ei[e];
    atomicAdd(&cnt[src], 1);
}

// ---- exclusive scan of 8192 counts (1 block)
__global__ void cpa_scan(const int* __restrict__ cnt, int* __restrict__ rowptr,
                         int* __restrict__ cursor) {
    __shared__ int part[256];
    int t = threadIdx.x;
    int base = t * 32;
    int s = 0;
    for (int k = 0; k < 32; ++k) s += cnt[base + k];
    part[t] = s;
    __syncthreads();
    if (t == 0) {
        int run = 0;
        for (int k = 0; k < 256; ++k) { int tmp = part[k]; part[k] = run; run += tmp; }
        rowptr[N_NODES] = run;
    }
    __syncthreads();
    int run = part[t];
    for (int k = 0; k < 32; ++k) {
        rowptr[base + k] = run;
        cursor[base + k] = run;
        run += cnt[base + k];
    }
}

// ---- scatter edges into CSR, key = (dst<<18)|e  (sortable by (dst, e))
__global__ void cpa_scatter(const int* __restrict__ ei, int* __restrict__ cursor,
                            int* __restrict__ keys) {
    int e = blockIdx.x * 256 + threadIdx.x;
    int src = ei[e];
    int dst = ei[NEDGE + e];
    int pos = atomicAdd(&cursor[src], 1);
    keys[pos] = (dst << 18) | e;
}

// ---- per-row sort by (dst,e) via wave-parallel bitonic (2 keys/lane, len<=128);
// mark all-but-last duplicate dst dead (numpy last-wins). No scratch, no LDS.
__global__ __launch_bounds__(256) void cpa_sortrows(const int* __restrict__ rowptr,
                                                    int* __restrict__ keys) {
    int row  = blockIdx.x * 4 + (threadIdx.x >> 6);   // one wave per row
    int lane = threadIdx.x & 63;
    int beg = rowptr[row], end = rowptr[row + 1];
    int len = end - beg;
    if (len > 128) len = 128;   // Poisson(32): impossible in practice
    const int idx0 = lane * 2, idx1 = lane * 2 + 1;
    int v0 = (idx0 < len) ? keys[beg + idx0] : 0x7FFFFFFF;
    int v1 = (idx1 < len) ? keys[beg + idx1] : 0x7FFFFFFF;

    #pragma unroll
    for (int k = 2; k <= 128; k <<= 1) {
        #pragma unroll
        for (int j = k >> 1; j >= 2; j >>= 1) {
            int ldist = j >> 1;                        // partner lane distance
            int p0 = __shfl_xor(v0, ldist);
            int p1 = __shfl_xor(v1, ldist);
            bool asc = (idx0 & k) == 0;                // same for both slots (k>=2)
            bool low = (idx0 & j) == 0;                // same for both slots (j>=2)
            int n0 = (low == asc) ? min(v0, p0) : max(v0, p0);
            int n1 = (low == asc) ? min(v1, p1) : max(v1, p1);
            v0 = n0; v1 = n1;
        }
        {   // j == 1: within-lane compare of the two slots
            bool asc = (idx0 & k) == 0;
            int lo = min(v0, v1), hi = max(v0, v1);
            v0 = asc ? lo : hi;
            v1 = asc ? hi : lo;
        }
    }

    // mark dead: element idx is dead iff idx+1 < len and dst(idx+1)==dst(idx).
    int nextv0 = __shfl_down(v0, 1);                   // lane+1's v0 = element idx1+1
    bool dead0 = (idx0 + 1 < len) && ((v0 >> 18) == (v1 >> 18));
    bool dead1 = (idx1 + 1 < len) && ((v1 >> 18) == (nextv0 >> 18));
    if (idx0 < len) keys[beg + idx0] = v0 | (dead0 ? 0x80000000 : 0);
    if (idx1 < len) keys[beg + idx1] = v1 | (dead1 ? 0x80000000 : 0);
}

// ---- flash attention over 64-row block, one column split (1024 cols)
__global__ __launch_bounds__(256) void cpa_flash(
    const short* __restrict__ Xbf, const short* __restrict__ Ybt,
    const float* __restrict__ es, const int* __restrict__ keys,
    const int* __restrict__ rowptr,
    float* __restrict__ msplit, float* __restrict__ lsplit,
    short* __restrict__ Opart)
{
    __shared__ short Xj[BR][136];     // X tile, rows j, stride 136 bf16 (272B, 16B-aligned)
    __shared__ short Yt[DX][72];      // V tile K-transposed: Yt[n][k]
    __shared__ short Pl[BR][72];      // P tile bf16 (C-layout -> A-layout round trip)
    __shared__ int   cur[BR];
    __shared__ int   rend_s[BR];
    __shared__ float dls[BR];

    const int tid   = threadIdx.x;
    const int lane  = tid & 63;
    const int w     = tid >> 6;       // wave 0..3 -> rows 16w..16w+15
    const int q     = lane >> 4;      // quad
    const int colid = lane & 15;

    const int ib = blockIdx.x;        // 0..127
    const int split = blockIdx.y;     // 0..SPLITS-1
    const int i0 = ib * BR;
    const int jstart = split * (N_NODES / SPLITS);

    // load Xi rows into Xj buffer, pull A-fragments to registers (once per block)
    for (int itr = 0; itr < 4; ++itr) {
        int idx = tid + itr * 256;
        int r = idx >> 4;
        int c8 = (idx & 15) << 3;
        *(int4*)(&Xj[r][c8]) = *(const int4*)(Xbf + (size_t)(i0 + r) * DX + c8);
    }
    __syncthreads();
    short8 afrag[4];
    #pragma unroll
    for (int kf = 0; kf < 4; ++kf)
        afrag[kf] = *(const short8*)&Xj[w * 16 + colid][kf * 32 + q * 8];  // wave w owns rows 16w..16w+15
    if (tid < BR) {
        int i = i0 + tid;
        int c = rowptr[i], e_ = rowptr[i + 1];
        while (c < e_) {
            int k = keys[c];
            int dst = (k >> 18) & 0x1FFF;
            if (dst >= jstart) break;
            ++c;
        }
        cur[tid] = c; rend_s[tid] = e_;
        dls[tid] = 0.f;
    }
    __syncthreads();

    float m_r[4] = {-1e30f, -1e30f, -1e30f, -1e30f};
    float l_r[4] = {0.f, 0.f, 0.f, 0.f};
    f32x4 O[8];
    #pragma unroll
    for (int t = 0; t < 8; ++t) O[t] = (f32x4){0.f, 0.f, 0.f, 0.f};

    for (int tt = 0; tt < TILES; ++tt) {
        const int j0 = jstart + tt * BC;
        // phase A: stage X_j and Y_t tiles
        for (int itr = 0; itr < 4; ++itr) {
            int idx = tid + itr * 256;
            int r = idx >> 4;
            int c8 = (idx & 15) << 3;
            *(int4*)(&Xj[r][c8]) = *(const int4*)(Xbf + (size_t)(j0 + r) * DX + c8);
        }
        for (int itr = 0; itr < 4; ++itr) {
            int idx = tid + itr * 256;
            int n = idx >> 3;
            int k8 = (idx & 7) << 3;
            *(int4*)(&Yt[n][k8]) = *(const int4*)(Ybt + (size_t)n * N_NODES + j0 + k8);
        }
        __syncthreads();  // B1

        // phase B: S = Xi·Xjᵀ (wave w: rows 16w..16w+15, cols 0..63)
        f32x4 S[4];
        #pragma unroll
        for (int st = 0; st < 4; ++st) {
            f32x4 acc = (f32x4){0.f, 0.f, 0.f, 0.f};
            #pragma unroll
            for (int kf = 0; kf < 4; ++kf) {
                short8 bfrag = *(const short8*)&Xj[st * 16 + colid][kf * 32 + q * 8];
                acc = __builtin_amdgcn_mfma_f32_16x16x32_bf16(afrag[kf], bfrag, acc, 0, 0, 0);
            }
            S[st] = acc;
        }
        // online softmax (C-layout: row = q*4+r local-16, col = st*16+colid)
        float mnew[4], alpha[4];
        #pragma unroll
        for (int r = 0; r < 4; ++r) {
            float mx = fmaxf(fmaxf(S[0][r], S[1][r]), fmaxf(S[2][r], S[3][r]));
            mx = fmaxf(mx, __shfl_xor(mx, 1));
            mx = fmaxf(mx, __shfl_xor(mx, 2));
            mx = fmaxf(mx, __shfl_xor(mx, 4));
            mx = fmaxf(mx, __shfl_xor(mx, 8));
            mnew[r] = fmaxf(m_r[r], mx);
            alpha[r] = __expf(m_r[r] - mnew[r]);
            m_r[r] = mnew[r];
        }
        float rsum[4] = {0.f, 0.f, 0.f, 0.f};
        short pb[4][4];
        #pragma unroll
        for (int st = 0; st < 4; ++st) {
            #pragma unroll
            for (int r = 0; r < 4; ++r) {
                float p = __expf(S[st][r] - mnew[r]);
                rsum[r] += p;
                pb[st][r] = f2bf(p);
            }
        }
        #pragma unroll
        for (int r = 0; r < 4; ++r) {
            float s_ = rsum[r];
            s_ += __shfl_xor(s_, 1);
            s_ += __shfl_xor(s_, 2);
            s_ += __shfl_xor(s_, 4);
            s_ += __shfl_xor(s_, 8);
            l_r[r] = l_r[r] * alpha[r] + s_;
            #pragma unroll
            for (int t = 0; t < 8; ++t) O[t][r] *= alpha[r];
        }
        // phase C: P -> LDS (bf16)
        #pragma unroll
        for (int st = 0; st < 4; ++st)
            #pragma unroll
            for (int r = 0; r < 4; ++r)
                Pl[w * 16 + q * 4 + r][st * 16 + colid] = pb[st][r];
        __syncthreads();  // B3

        // phase C2: sparse bias: P *= exp(bias) at live edges; track Δl per row
        if (tid < BR) {
            int c = cur[tid];
            const int e_ = rend_s[tid];
            const int jend = j0 + BC;
            float dlocal = 0.f;
            while (c < e_) {
                int k = keys[c];
                int dst = (k >> 18) & 0x1FFF;
                if (dst >= jend) break;
                ++c;
                if (k >= 0) {  // live (last duplicate wins)
                    int ec = dst - j0;
                    float old = bf2f(Pl[tid][ec]);
                    float nw = old * __expf(es[k & 0x3FFFF]);
                    Pl[tid][ec] = f2bf(nw);
                    dlocal += nw - old;
                }
            }
            cur[tid] = c;
            dls[tid] = dlocal;
        }
        __syncthreads();  // B3.5

        // phase D: l += Δl; O += P·Y
        #pragma unroll
        for (int r = 0; r < 4; ++r)
            l_r[r] += dls[w * 16 + q * 4 + r];

        short8 pf0 = *(const short8*)&Pl[w * 16 + colid][q * 8];
        short8 pf1 = *(const short8*)&Pl[w * 16 + colid][32 + q * 8];
        #pragma unroll
        for (int t = 0; t < 8; ++t) {
            short8 b0 = *(const short8*)&Yt[t * 16 + colid][q * 8];
            short8 b1 = *(const short8*)&Yt[t * 16 + colid][32 + q * 8];
            O[t] = __builtin_amdgcn_mfma_f32_16x16x32_bf16(pf0, b0, O[t], 0, 0, 0);
            O[t] = __builtin_amdgcn_mfma_f32_16x16x32_bf16(pf1, b1, O[t], 0, 0, 0);
        }
        __syncthreads();  // B4 (protect tiles for next iteration)
    }

    // epilogue: store partial m, l, O (O as bf16)
    const int ibase = i0 + w * 16 + q * 4;
    #pragma unroll
    for (int r = 0; r < 4; ++r) {
        if (colid == r) {
            msplit[(size_t)split * N_NODES + ibase + r] = m_r[r];
            lsplit[(size_t)split * N_NODES + ibase + r] = l_r[r];
        }
    }
    #pragma unroll
    for (int t = 0; t < 8; ++t) {
        #pragma unroll
        for (int r = 0; r < 4; ++r) {
            size_t off = ((size_t)split * N_NODES + ibase + r) * DX + t * 16 + colid;
            Opart[off] = f2bf(O[t][r]);
        }
    }
}

// ---- merge splits + normalize + write [new_mag | new_phase]
__global__ void cpa_merge(const float* __restrict__ msplit, const float* __restrict__ lsplit,
                          const short* __restrict__ Opart, float* __restrict__ out) {
    int gid = blockIdx.x * 256 + threadIdx.x;   // N*128 threads
    int i = gid >> 7;
    int c = gid & 127;
    float mm = -1e30f;
    #pragma unroll
    for (int s = 0; s < SPLITS; ++s) mm = fmaxf(mm, msplit[(size_t)s * N_NODES + i]);
    float den = 0.f, num = 0.f;
    #pragma unroll
    for (int s = 0; s < SPLITS; ++s) {
        float wgt = __expf(msplit[(size_t)s * N_NODES + i] - mm);
        den += lsplit[(size_t)s * N_NODES + i] * wgt;
        num += bf2f(Opart[((size_t)s * N_NODES + i) * DX + c]) * wgt;
    }
    float val = num / den;
    if (c < 64) out[(size_t)i * 64 + c] = val;
    else        out[(size_t)N_NODES * 64 + (size_t)i * 64 + (c - 64)] = val;
}

extern "C" void kernel_launch(void* const* d_in, const int* in_sizes, int n_in,
                              void* d_out, int out_size, void* d_ws, size_t ws_size,
                              hipStream_t stream)
{
    const float* mag   = (const float*)d_in[0];
    const float* phase = (const float*)d_in[1];
    const int*   ei    = (const int*)d_in[2];     // edge_index [2][E] (int32 per harness)
    const float* ea    = (const float*)d_in[3];
    const float* W     = (const float*)d_in[4];
    const float* b     = (const float*)d_in[5];
    float* out = (float*)d_out;

    char* ws = (char*)d_ws;
    short* Xbf    = (short*)(ws + 0);               // 2 MB
    short* Ybt    = (short*)(ws + 2097152);         // 2 MB
    float* es     = (float*)(ws + 4194304);         // 1 MB
    int*   keys   = (int*)  (ws + 5242880);         // 1 MB
    int*   rowptr = (int*)  (ws + 6291456);         // 36 KB slot
    int*   cnt    = (int*)  (ws + 6328320);         // 32 KB
    int*   cursor = (int*)  (ws + 6361088);         // 32 KB
    float* wsb    = (float*)(ws + 6393856);         // 256 B
    float* msplit = (float*)(ws + 6394112);         // 256 KB (8 splits)
    float* lsplit = (float*)(ws + 6656256);         // 256 KB
    short* Opart  = (short*)(ws + 6918400);         // 16 MB (bf16, 8 splits)

    hipMemsetAsync(cnt, 0, N_NODES * sizeof(int), stream);
    cpa_prep_x<<<N_NODES * DDIM / 256, 256, 0, stream>>>(mag, phase, Xbf);
    cpa_prep_yt<<<(N_NODES / 64) * 2, 256, 0, stream>>>(mag, phase, Ybt);
    cpa_prep_w<<<1, 64, 0, stream>>>(W, b, wsb);
    cpa_edges<<<NEDGE / 256, 256, 0, stream>>>(ei, ea, wsb, es, cnt);
    cpa_scan<<<1, 256, 0, stream>>>(cnt, rowptr, cursor);
    cpa_scatter<<<NEDGE / 256, 256, 0, stream>>>(ei, cursor, keys);
    cpa_sortrows<<<N_NODES / 4, 256, 0, stream>>>(rowptr, keys);
    cpa_flash<<<dim3(N_NODES / BR, SPLITS), 256, 0, stream>>>(Xbf, Ybt, es, keys, rowptr,
                                                              msplit, lsplit, Opart);
    cpa_merge<<<N_NODES * DX / 256, 256, 0, stream>>>(msplit, lsplit, Opart, out);
}